// Round 4
// baseline (95.380 us; speedup 1.0000x reference)
//
#include <hip/hip_runtime.h>
#include <hip/hip_fp16.h>

#define D_VOCAB 262
#define D_EMB   128
#define KW      5
#define NCHAR   16
#define NKO     (KW * D_EMB)      // 640 halfs per vocab row (1280 B)

typedef _Float16 h2 __attribute__((ext_vector_type(2)));
typedef _Float16 h8 __attribute__((ext_vector_type(8)));

// d_ws layout: P at offset 0 : 262*640 halfs = 335,360 B (fp16, P[v][k][o]).
// (Wt2 intermediate eliminated in R4.)

// ---------------------------------------------------------------------------
// Fused stages 1+2 (R4): P[v][k*128+o] = sum_i emb[v][i] * cw[o*640+i*5+k],
// transpose folded into LDS staging. Block = (o-tile of 32, v-group of 8):
//   stage: reads the CONTIGUOUS 80 KB slab cw[o0*640 .. o0*640+20480) --
//          src = o0*640 + u exactly -- and scatters to Btile[r][oc] with
//          row-pad 33 (write bank = (r+oc)%32, conflict-free).
//   compute: 160 active lanes (k = t>>5 < 5, oc = t&31), 8 v-row accs each,
//          Btile read bank-consecutive, emb_s reads are broadcasts.
// L2 traffic 132*80KB ~ 10 MB (vs 86 MB in R3's stage 2) and ONE launch
// replaces two (stage 1 was pure launch overhead: 640 KB of traffic).
// Accumulation: single acc, i ascending = R0-R2's passing config.
// ---------------------------------------------------------------------------
#define VG 8                         // vocab rows per block
#define OT 32                        // output channels per block
#define BT_PAD 33                    // Btile row stride (floats)

__global__ __launch_bounds__(256) void fused_P_kernel(
    const float* __restrict__ emb, const float* __restrict__ cw,
    __half* __restrict__ P) {
  __shared__ float Btile[NKO * BT_PAD];      // 640 rows (r=i*5+k) x 33: 84,480 B
  __shared__ float emb_s[VG][D_EMB];         // 4 KB

  const int tid = threadIdx.x;
  const int ot  = blockIdx.x & 3;            // o-tile 0..3
  const int vg  = blockIdx.x >> 2;           // v-group 0..32
  const int o0  = ot * OT;
  const int v0  = vg * VG;

  // ---- stage W slab: contiguous read, scattered conflict-free LDS write ----
  const float* slab = cw + o0 * NKO;         // 20480 contiguous floats
  for (int u = tid; u < OT * NKO; u += 256) {
    const int oc = u / NKO;                  // 0..31
    const int r  = u - oc * NKO;             // i*5+k, 0..639
    Btile[r * BT_PAD + oc] = slab[u];
  }
  // ---- stage emb rows (zero-fill past vocab end) ----
  for (int u = tid; u < VG * D_EMB; u += 256) {
    const int vr  = u >> 7;
    const int col = u & 127;
    const int v   = v0 + vr;
    emb_s[vr][col] = (v < D_VOCAB) ? emb[v * D_EMB + col] : 0.f;
  }
  __syncthreads();

  // ---- compute: 160 active lanes, 8 outputs each ----
  if (tid < KW * OT) {
    const int k  = tid >> 5;                 // 0..4
    const int oc = tid & 31;                 // 0..31
    const float* colp = Btile + k * BT_PAD + oc;

    float acc[VG];
#pragma unroll
    for (int vr = 0; vr < VG; ++vr) acc[vr] = 0.f;

#pragma unroll 4
    for (int i = 0; i < D_EMB; ++i) {
      const float b = colp[i * (KW * BT_PAD)];   // bank-consecutive across lanes
#pragma unroll
      for (int vr = 0; vr < VG; ++vr) acc[vr] += emb_s[vr][i] * b;
    }

#pragma unroll
    for (int vr = 0; vr < VG; ++vr) {
      const int v = v0 + vr;
      if (v < D_VOCAB)
        P[v * NKO + k * D_EMB + o0 + oc] = __float2half(acc[vr]);
    }
  }
}

// ---------------------------------------------------------------------------
// Main (unchanged from R3, byte-identical output): LDS-resident P quarter
// (8 channel-quarters of CH=16, 46 KB LDS rows padded to 176 B, 2 blocks/CU,
// 32 waves/CU). Per-lane direct id loads; tap reads via ds_read_b128.
// ---------------------------------------------------------------------------
#define CH       16                 // channels per quarter
#define NQ       (D_EMB / CH)       // 8 quarters
#define VSTRIDE  176                // LDS bytes per vocab row: 5*16*2 + 16 pad
#define LDS_SZ   (D_VOCAB * VSTRIDE)  // 46,112 B
#define SEQ_PER_BLOCK 512           // 16 waves * 32 seqs

__global__ __launch_bounds__(1024) void conv_char_main_kernel(
    const int* __restrict__ ids, const _Float16* __restrict__ P,
    const float* __restrict__ bias, float* __restrict__ out) {
  __shared__ __attribute__((aligned(16))) char Plds[LDS_SZ];

  const int tid  = threadIdx.x;
  const int lane = tid & 63;
  const int wid  = tid >> 6;            // wave in block, 0..15
  const int q    = blockIdx.x >> 6;     // channel-quarter 0..7  (nsb = 64)
  const int sb   = blockIdx.x & 63;     // seq-block 0..63

  // ---- stage this quarter of P into LDS (46 KB, coalesced 16-B units) ----
  for (int u = tid; u < LDS_SZ / 16; u += 1024) {
    const int L = u * 16;
    const int v = L / VSTRIDE;
    const int r = L - v * VSTRIDE;
    if (r < 160) {
      const h8 val = *(const h8*)(P + v * NKO + (r >> 5) * D_EMB + q * CH + ((r & 31) >> 1));
      *(h8*)(Plds + L) = val;
    }
  }
  __syncthreads();

  const int grp = lane >> 1;            // seq within wave, 0..31
  const int t   = lane & 1;             // half of the 16-ch quarter
  const int seq = sb * SEQ_PER_BLOCK + wid * 32 + grp;

  const int4* idp = (const int4*)(ids + seq * NCHAR);
  const int4 ia = idp[0];
  const int4 ib = idp[1];
  const int4 ic = idp[2];
  const int4 id4 = idp[3];

  h8 win[5];
#pragma unroll
  for (int w = 0; w < 5; ++w) win[w] = (h8)(_Float16)0.f;
  h8 vmax = (h8)(_Float16)(-60000.f);

  const char* Pl = Plds + t * 16;       // this lane's 16-B slot within k-row

#pragma unroll
  for (int j = 0; j < NCHAR; ++j) {
    const int idj = (j < 4)  ? ((const int*)&ia)[j & 3]
                  : (j < 8)  ? ((const int*)&ib)[j & 3]
                  : (j < 12) ? ((const int*)&ic)[j & 3]
                             : ((const int*)&id4)[j & 3];
    const char* row = Pl + idj * VSTRIDE;
#pragma unroll
    for (int k = 0; k < KW; ++k) {
      const int c = j + 2 - k;          // output position fed
      if (c >= 0 && c < NCHAR) {
        const h8 val = *(const h8*)(row + k * 32);   // ds_read_b128, imm off
        win[c % 5] += val;                           // 4x v_pk_add_f16
      }
    }
    if (j >= 2) {                       // y[j-2] complete
      const int w = (j - 2) % 5;
      vmax = __builtin_elementwise_max(vmax, win[w]);
      win[w] = (h8)(_Float16)0.f;
    }
  }
  vmax = __builtin_elementwise_max(vmax, win[14 % 5]);
  vmax = __builtin_elementwise_max(vmax, win[15 % 5]);

  const int o = q * CH + t * 8;         // this lane's 8 output channels
  const float4 b0 = *(const float4*)(bias + o);
  const float4 b1 = *(const float4*)(bias + o + 4);
  float* op = out + (size_t)seq * D_EMB + o;
  float4 r0, r1;
  r0.x = (float)vmax[0] + b0.x;
  r0.y = (float)vmax[1] + b0.y;
  r0.z = (float)vmax[2] + b0.z;
  r0.w = (float)vmax[3] + b0.w;
  r1.x = (float)vmax[4] + b1.x;
  r1.y = (float)vmax[5] + b1.y;
  r1.z = (float)vmax[6] + b1.z;
  r1.w = (float)vmax[7] + b1.w;
  *(float4*)op = r0;
  *(float4*)(op + 4) = r1;
}

// ---------------------------------------------------------------------------
// Inputs: d_in[0] ids (B*W*C int32), d_in[1] lengths (unused),
//         d_in[2] emb (262x128 f32), d_in[3] conv_w (128x128x5 f32),
//         d_in[4] conv_b (128 f32).  Output: (B*W*128) f32.
// ---------------------------------------------------------------------------
extern "C" void kernel_launch(void* const* d_in, const int* in_sizes, int n_in,
                              void* d_out, int out_size, void* d_ws, size_t ws_size,
                              hipStream_t stream) {
  const int*   input = (const int*)d_in[0];
  const float* emb   = (const float*)d_in[2];
  const float* cw    = (const float*)d_in[3];
  const float* cb    = (const float*)d_in[4];
  float* out = (float*)d_out;

  _Float16* P = (_Float16*)d_ws;

  const int n_seq = in_sizes[0] / NCHAR;   // B*W = 32768

  // fused transpose + P-GEMM: 4 o-tiles x 33 v-groups = 132 blocks
  fused_P_kernel<<<4 * 33, 256, 0, stream>>>(emb, cw, (__half*)P);

  // 8 quarters x (n_seq/512) seq-blocks = 512 blocks of 1024 threads
  const int nsb = n_seq / SEQ_PER_BLOCK;   // 64 (kernel hardcodes the >>6 split)
  conv_char_main_kernel<<<NQ * nsb, 1024, 0, stream>>>(input, P, cb, out);
}

// Round 5
// 92.280 us; speedup vs baseline: 1.0336x; 1.0336x over previous
//
#include <hip/hip_runtime.h>
#include <hip/hip_fp16.h>

#define D_VOCAB 262
#define D_EMB   128
#define KW      5
#define NCHAR   16
#define NKO     (KW * D_EMB)      // 640 halfs per vocab row (1280 B)

typedef _Float16 h2 __attribute__((ext_vector_type(2)));
typedef _Float16 h8 __attribute__((ext_vector_type(8)));

// d_ws layout:
//   P   at offset 0       : 262*640 halfs = 335,360 B (fp16 table, P[v][k][o])
//   Wt2 at offset 335,872 : 128*640 floats = 327,680 B, Wt2[i][ko]
//
// R5 = exact revert to R3 (measured best, 92.49 us). R4's fused stage
// regressed (+2.9 us): 84.5 KB LDS -> 1 block/CU, 160/256 lanes active,
// latency-bound. Two small launches win.

// ---------------------------------------------------------------------------
// Stage 1: Wt2[i*640 + k*128 + o] = conv_w[o*640 + i*5 + k]. ~2 us.
// ---------------------------------------------------------------------------
__global__ __launch_bounds__(256) void transpose_w_kernel(
    const float* __restrict__ cw, float* __restrict__ Wt2) {
  const int gid = blockIdx.x * 256 + threadIdx.x;   // 0..81919
  const float val = cw[gid];
  const int o = gid / 640;
  const int r = gid - o * 640;
  const int i = r / 5;
  const int k = r - i * 5;
  Wt2[i * NKO + k * D_EMB + o] = val;
}

// ---------------------------------------------------------------------------
// Stage 2: block = vocab row v, 640 threads (t = ko). Every Wt2 read is
// a fully-contiguous 2560-B sweep per i (perfect coalescing), emb row staged
// once for all 5 k, dual accumulators for ILP. ~3.5 us.
// ---------------------------------------------------------------------------
__global__ __launch_bounds__(640) void compute_P_kernel(
    const float* __restrict__ emb, const float* __restrict__ Wt2,
    __half* __restrict__ P) {
  __shared__ float emb_s[D_EMB];
  const int v = blockIdx.x;             // 0..261
  const int t = threadIdx.x;            // ko = k*128+o
  if (t < D_EMB) emb_s[t] = emb[v * D_EMB + t];
  __syncthreads();

  const float* col = Wt2 + t;
  float a0 = 0.f, a1 = 0.f;
#pragma unroll 8
  for (int i = 0; i < D_EMB; i += 2) {
    a0 += emb_s[i]     * col[i * NKO];
    a1 += emb_s[i + 1] * col[(i + 1) * NKO];
  }
  P[v * NKO + t] = __float2half(a0 + a1);
}

// ---------------------------------------------------------------------------
// Main: LDS-resident P quarter (8 channel-quarters of CH=16, 46 KB LDS,
// rows padded to 176 B, 2 blocks/CU, 32 waves/CU). Per-lane direct id loads
// (VMEM pipe, keeping the DS pipe for tap reads); taps via ds_read_b128.
// At the DS-byte floor: 620 MB of taps / ~52 TB/s ~ 12-14 us.
// ---------------------------------------------------------------------------
#define CH       16                 // channels per quarter
#define NQ       (D_EMB / CH)       // 8 quarters
#define VSTRIDE  176                // LDS bytes per vocab row: 5*16*2 + 16 pad
#define LDS_SZ   (D_VOCAB * VSTRIDE)  // 46,112 B
#define SEQ_PER_BLOCK 512           // 16 waves * 32 seqs

__global__ __launch_bounds__(1024) void conv_char_main_kernel(
    const int* __restrict__ ids, const _Float16* __restrict__ P,
    const float* __restrict__ bias, float* __restrict__ out) {
  __shared__ __attribute__((aligned(16))) char Plds[LDS_SZ];

  const int tid  = threadIdx.x;
  const int lane = tid & 63;
  const int wid  = tid >> 6;            // wave in block, 0..15
  const int q    = blockIdx.x >> 6;     // channel-quarter 0..7  (nsb = 64)
  const int sb   = blockIdx.x & 63;     // seq-block 0..63

  // ---- stage this quarter of P into LDS (46 KB, coalesced 16-B units) ----
  for (int u = tid; u < LDS_SZ / 16; u += 1024) {
    const int L = u * 16;
    const int v = L / VSTRIDE;
    const int r = L - v * VSTRIDE;
    if (r < 160) {
      const h8 val = *(const h8*)(P + v * NKO + (r >> 5) * D_EMB + q * CH + ((r & 31) >> 1));
      *(h8*)(Plds + L) = val;
    }
  }
  __syncthreads();

  const int grp = lane >> 1;            // seq within wave, 0..31
  const int t   = lane & 1;             // half of the 16-ch quarter
  const int seq = sb * SEQ_PER_BLOCK + wid * 32 + grp;

  const int4* idp = (const int4*)(ids + seq * NCHAR);
  const int4 ia = idp[0];
  const int4 ib = idp[1];
  const int4 ic = idp[2];
  const int4 id4 = idp[3];

  h8 win[5];
#pragma unroll
  for (int w = 0; w < 5; ++w) win[w] = (h8)(_Float16)0.f;
  h8 vmax = (h8)(_Float16)(-60000.f);

  const char* Pl = Plds + t * 16;       // this lane's 16-B slot within k-row

#pragma unroll
  for (int j = 0; j < NCHAR; ++j) {
    const int idj = (j < 4)  ? ((const int*)&ia)[j & 3]
                  : (j < 8)  ? ((const int*)&ib)[j & 3]
                  : (j < 12) ? ((const int*)&ic)[j & 3]
                             : ((const int*)&id4)[j & 3];
    const char* row = Pl + idj * VSTRIDE;
#pragma unroll
    for (int k = 0; k < KW; ++k) {
      const int c = j + 2 - k;          // output position fed
      if (c >= 0 && c < NCHAR) {
        const h8 val = *(const h8*)(row + k * 32);   // ds_read_b128, imm off
        win[c % 5] += val;                           // 4x v_pk_add_f16
      }
    }
    if (j >= 2) {                       // y[j-2] complete
      const int w = (j - 2) % 5;
      vmax = __builtin_elementwise_max(vmax, win[w]);
      win[w] = (h8)(_Float16)0.f;
    }
  }
  vmax = __builtin_elementwise_max(vmax, win[14 % 5]);
  vmax = __builtin_elementwise_max(vmax, win[15 % 5]);

  const int o = q * CH + t * 8;         // this lane's 8 output channels
  const float4 b0 = *(const float4*)(bias + o);
  const float4 b1 = *(const float4*)(bias + o + 4);
  float* op = out + (size_t)seq * D_EMB + o;
  float4 r0, r1;
  r0.x = (float)vmax[0] + b0.x;
  r0.y = (float)vmax[1] + b0.y;
  r0.z = (float)vmax[2] + b0.z;
  r0.w = (float)vmax[3] + b0.w;
  r1.x = (float)vmax[4] + b1.x;
  r1.y = (float)vmax[5] + b1.y;
  r1.z = (float)vmax[6] + b1.z;
  r1.w = (float)vmax[7] + b1.w;
  *(float4*)op = r0;
  *(float4*)(op + 4) = r1;
}

// ---------------------------------------------------------------------------
// Inputs: d_in[0] ids (B*W*C int32), d_in[1] lengths (unused),
//         d_in[2] emb (262x128 f32), d_in[3] conv_w (128x128x5 f32),
//         d_in[4] conv_b (128 f32).  Output: (B*W*128) f32.
// ---------------------------------------------------------------------------
extern "C" void kernel_launch(void* const* d_in, const int* in_sizes, int n_in,
                              void* d_out, int out_size, void* d_ws, size_t ws_size,
                              hipStream_t stream) {
  const int*   input = (const int*)d_in[0];
  const float* emb   = (const float*)d_in[2];
  const float* cw    = (const float*)d_in[3];
  const float* cb    = (const float*)d_in[4];
  float* out = (float*)d_out;

  _Float16* P   = (_Float16*)d_ws;
  float*    Wt2 = (float*)((char*)d_ws + 335872);

  const int n_seq = in_sizes[0] / NCHAR;   // B*W = 32768

  transpose_w_kernel<<<320, 256, 0, stream>>>(cw, Wt2);          // 81,920 elems
  compute_P_kernel<<<D_VOCAB, 640, 0, stream>>>(emb, Wt2, (__half*)P);

  // 8 quarters x (n_seq/512) seq-blocks = 512 blocks of 1024 threads
  const int nsb = n_seq / SEQ_PER_BLOCK;   // 64 (kernel hardcodes the >>6 split)
  conv_char_main_kernel<<<NQ * nsb, 1024, 0, stream>>>(input, P, cb, out);
}